// Round 9
// baseline (168.377 us; speedup 1.0000x reference)
//
#include <hip/hip_runtime.h>
#include <hip/hip_bf16.h>

typedef __attribute__((ext_vector_type(8))) short short8;
typedef __attribute__((ext_vector_type(4))) short short4v;
typedef __attribute__((ext_vector_type(4))) float f32x4;
typedef __attribute__((ext_vector_type(8))) __bf16 bf16x8;

#define BB 8
#define CC 64
#define NN 65536        // H*W = 256*256
#define SPLIT1 64       // k1 blocks per batch (512 total = 2 blocks/CU)
#define COLS1 (NN / SPLIT1)   // 1024 cols per k1 block
#define TILE_C 64             // fp32 tile cols: 64 x 64 x 4B = 16 KB per buffer
#define NT1 (COLS1 / TILE_C)  // 16 tiles per block
#define SPLIT3 128      // k3 blocks per batch

// MEASUREMENT ROUND: internal repeats to push k1/k3 dispatches above the
// ~79 us harness-fill threshold so they surface in rocprof top-5 with their
// own counters. Output is bit-identical (idempotent repeats). Remove next round.
#define REP1 4
#define REP3 2

__device__ inline short f2bf(float f) {
    __hip_bfloat16 h = __float2bfloat16(f);
    return __builtin_bit_cast(short, h);
}

// --- MFMA wrapper: tolerate either short8 or bf16x8 builtin signature ---
template <typename V>
__device__ inline auto mfma_bf16_impl(V a, V b, f32x4 c, int)
    -> decltype(__builtin_amdgcn_mfma_f32_16x16x32_bf16(a, b, c, 0, 0, 0)) {
    return __builtin_amdgcn_mfma_f32_16x16x32_bf16(a, b, c, 0, 0, 0);
}
template <typename V>
__device__ inline f32x4 mfma_bf16_impl(V a, V b, f32x4 c, long) {
    bf16x8 a2 = __builtin_bit_cast(bf16x8, a);
    bf16x8 b2 = __builtin_bit_cast(bf16x8, b);
    return __builtin_amdgcn_mfma_f32_16x16x32_bf16(a2, b2, c, 0, 0, 0);
}
__device__ inline f32x4 mfma16(short8 a, short8 b, f32x4 c) {
    return mfma_bf16_impl(a, b, c, 0);
}

// ---- async global->LDS staging of one 64x64 fp32 tile (16 KB) ---------------
__device__ inline void stage_tile(const float* __restrict__ xb, int colbase,
                                  float* buf, int tid) {
    const int slot  = tid & 15;
    const int rg    = tid >> 4;
    const int gbyte = (slot ^ rg) << 4;  // pre-swizzled source byte
#pragma unroll
    for (int i = 0; i < 4; ++i) {
        const int row = i * 16 + rg;
        const float* gp = xb + (size_t)row * NN + colbase + (gbyte >> 2);
        float* lp = buf + i * 1024 + tid * 4;
        __builtin_amdgcn_global_load_lds(
            (const __attribute__((address_space(1))) void*)gp,
            (__attribute__((address_space(3))) void*)lp, 16, 0, 0);
    }
}

__device__ inline void lds_read8(const float* buf, int row, int c0, float* v) {
    const char* rb = (const char*)(buf + row * TILE_C);
    const int swz = (row & 15) << 4;
    const f32x4 u0 = *reinterpret_cast<const f32x4*>(rb + ((c0 * 4) ^ swz));
    const f32x4 u1 = *reinterpret_cast<const f32x4*>(rb + (((c0 * 4) + 16) ^ swz));
    v[0] = u0[0]; v[1] = u0[1]; v[2] = u0[2]; v[3] = u0[3];
    v[4] = u1[0]; v[5] = u1[1]; v[6] = u1[2]; v[7] = u1[3];
}

__device__ inline short8 cvt8(const float* v) {
    short8 r;
#pragma unroll
    for (int j = 0; j < 8; ++j) r[j] = f2bf(v[j]);
    return r;
}

// ------- Kernel 1: partial Gram (bf16 MFMA) + channel sums -------------------
__global__ __launch_bounds__(256) void k1_gram(const float* __restrict__ x,
                                               float* __restrict__ partialG,
                                               float* __restrict__ partialS) {
    __shared__ float lbuf[4][CC * TILE_C];
    const int blk  = blockIdx.x;
    const int b    = blk / SPLIT1;
    const int s    = blk % SPLIT1;
    const int tid  = threadIdx.x;
    const int w    = tid >> 6, lane = tid & 63, lg = lane >> 4, lr = lane & 15;
    const float* xb = x + (size_t)b * CC * NN;
    const int colbase0 = s * COLS1;

    for (int rep = 0; rep < REP1; ++rep) {   // measurement repeat (idempotent)
        f32x4 acc[4];
#pragma unroll
        for (int dt = 0; dt < 4; ++dt) acc[dt] = (f32x4){0.f, 0.f, 0.f, 0.f};
        float asum = 0.f;

        stage_tile(xb, colbase0 + 0 * TILE_C, lbuf[0], tid);
        stage_tile(xb, colbase0 + 1 * TILE_C, lbuf[1], tid);
        stage_tile(xb, colbase0 + 2 * TILE_C, lbuf[2], tid);

        for (int t = 0; t < NT1; ++t) {
            if (t + 2 < NT1) {
                asm volatile("s_waitcnt vmcnt(8) lgkmcnt(0)" ::: "memory");
            } else if (t + 1 < NT1) {
                asm volatile("s_waitcnt vmcnt(4) lgkmcnt(0)" ::: "memory");
            } else {
                asm volatile("s_waitcnt vmcnt(0) lgkmcnt(0)" ::: "memory");
            }
            __builtin_amdgcn_s_barrier();
            if (t + 3 < NT1)
                stage_tile(xb, colbase0 + (t + 3) * TILE_C, lbuf[(t + 3) & 3], tid);

            const float* buf = lbuf[t & 3];
#pragma unroll
            for (int kk = 0; kk < TILE_C / 32; ++kk) {
                const int c0 = kk * 32 + lg * 8;
                float av[8];
                lds_read8(buf, w * 16 + lr, c0, av);
#pragma unroll
                for (int j = 0; j < 8; ++j) asum += av[j];
                const short8 af = cvt8(av);
#pragma unroll
                for (int dt = 0; dt < 4; ++dt) {
                    short8 bf;
                    if (dt == w) {
                        bf = af;
                    } else {
                        float bv[8];
                        lds_read8(buf, dt * 16 + lr, c0, bv);
                        bf = cvt8(bv);
                    }
                    acc[dt] = mfma16(af, bf, acc[dt]);
                }
            }
        }
#pragma unroll
        for (int dt = 0; dt < 4; ++dt) {
#pragma unroll
            for (int r = 0; r < 4; ++r) {
                const int c = w * 16 + lg * 4 + r;
                const int d = dt * 16 + lr;
                partialG[(size_t)blk * 4096 + c * 64 + d] = acc[dt][r];
            }
        }
        float v = asum;
        v += __shfl_xor(v, 16);
        v += __shfl_xor(v, 32);
        if (lg == 0) partialS[blk * CC + w * 16 + lr] = v;
        __syncthreads();
    }
}

// ---------------- Kernel 2a: reduce partial Gram over splits ----------------
__global__ __launch_bounds__(256) void k2a_reduceG(const float* __restrict__ partialG,
                                                   float* __restrict__ Gsum) {
    const int gid = blockIdx.x * 256 + threadIdx.x;   // 0..32767
    const int b = gid >> 12;
    const int e = gid & 4095;
    float s = 0.f;
    for (int sp = 0; sp < SPLIT1; ++sp)
        s += partialG[(((size_t)(b * SPLIT1 + sp)) << 12) + e];
    Gsum[gid] = s;
}

// ------- Kernel 2b: means, energy, softmax -> att(bf16) + offsets -----------
__global__ __launch_bounds__(256) void k2b_softmax(const float* __restrict__ partialS,
                                                   const float* __restrict__ Gsum,
                                                   unsigned short* __restrict__ att,
                                                   float* __restrict__ offs) {
    __shared__ float mu[CC];
    __shared__ float ener[CC * CC];
    const int b = blockIdx.x;
    const int tid = threadIdx.x;
    if (tid < CC) {
        float s = 0.f;
        for (int sp = 0; sp < SPLIT1; ++sp) s += partialS[(b * SPLIT1 + sp) * CC + tid];
        mu[tid] = s * (1.f / NN);
    }
    __syncthreads();
    const float inv_n = 1.f / NN;
#pragma unroll
    for (int k = 0; k < 16; ++k) {
        const int e = tid + k * 256;
        const int c = e >> 6, d = e & 63;
        ener[e] = Gsum[(b << 12) + e] * inv_n - mu[c] * mu[d];
    }
    __syncthreads();
    const int w = tid >> 6, lane = tid & 63;
    for (int i = 0; i < 16; ++i) {
        const int c = w * 16 + i;
        const float v = ener[c * 64 + lane];
        float m = v;
        for (int off = 32; off > 0; off >>= 1) m = fmaxf(m, __shfl_xor(m, off));
        const float ev = __expf(v - m);
        float sum = ev;
        for (int off = 32; off > 0; off >>= 1) sum += __shfl_xor(sum, off);
        const float a = ev / sum;
        att[(b << 12) + c * 64 + lane] = (unsigned short)f2bf(a);
        float o = a * mu[lane];
        for (int off = 32; off > 0; off >>= 1) o += __shfl_xor(o, off);
        if (lane == 0) offs[b * CC + c] = o;
    }
}

// ---------------- Kernel 3: out = gamma * (A @ x - offset) ------------------
__global__ __launch_bounds__(256) void k3_apply(const float* __restrict__ x,
                                                const unsigned short* __restrict__ att,
                                                const float* __restrict__ offs,
                                                const float* __restrict__ gamma,
                                                float* __restrict__ out) {
    const int blk  = blockIdx.x;
    const int b    = blk / SPLIT3;
    const int s    = blk % SPLIT3;
    const int tid  = threadIdx.x;
    const int w    = tid >> 6, lane = tid & 63, lg = lane >> 4, lr = lane & 15;
    const float g  = gamma[0];

    for (int rep = 0; rep < REP3; ++rep) {   // measurement repeat (idempotent)
        short8 afr[4][2];
#pragma unroll
        for (int ct = 0; ct < 4; ++ct)
#pragma unroll
            for (int ks = 0; ks < 2; ++ks)
                afr[ct][ks] = *reinterpret_cast<const short8*>(
                    att + (((size_t)b) << 12) + (ct * 16 + lr) * 64 + ks * 32 + lg * 8);

        float offv[4][4];
#pragma unroll
        for (int ct = 0; ct < 4; ++ct)
#pragma unroll
            for (int r = 0; r < 4; ++r)
                offv[ct][r] = offs[b * CC + ct * 16 + lg * 4 + r];

        const int colblock = s * (NN / SPLIT3);
        const int GROUPS = (NN / SPLIT3) / (4 * 64);   // =2
        for (int itg = 0; itg < GROUPS; ++itg) {
            const int n0 = colblock + (w * GROUPS + itg) * 64;
            f32x4 acc[4][4];
#pragma unroll
            for (int ph = 0; ph < 4; ++ph)
#pragma unroll
                for (int ct = 0; ct < 4; ++ct) acc[ph][ct] = (f32x4){0.f, 0.f, 0.f, 0.f};

#pragma unroll
            for (int ks = 0; ks < 2; ++ks) {
                short8 bfr[4];
                const int d0 = ks * 32 + lg * 8;
                const float* xp = x + ((size_t)(b * CC + d0)) * NN + n0 + lr * 4;
#pragma unroll
                for (int j = 0; j < 8; ++j) {
                    const float4 v = *reinterpret_cast<const float4*>(xp + (size_t)j * NN);
                    bfr[0][j] = f2bf(v.x);
                    bfr[1][j] = f2bf(v.y);
                    bfr[2][j] = f2bf(v.z);
                    bfr[3][j] = f2bf(v.w);
                }
#pragma unroll
                for (int ct = 0; ct < 4; ++ct) {
#pragma unroll
                    for (int ph = 0; ph < 4; ++ph)
                        acc[ph][ct] = mfma16(afr[ct][ks], bfr[ph], acc[ph][ct]);
                }
            }
#pragma unroll
            for (int ct = 0; ct < 4; ++ct) {
#pragma unroll
                for (int r = 0; r < 4; ++r) {
                    const int c = ct * 16 + lg * 4 + r;
                    const float o = offv[ct][r];
                    f32x4 vs;
                    vs[0] = g * (acc[0][ct][r] - o);
                    vs[1] = g * (acc[1][ct][r] - o);
                    vs[2] = g * (acc[2][ct][r] - o);
                    vs[3] = g * (acc[3][ct][r] - o);
                    __builtin_nontemporal_store(
                        vs, reinterpret_cast<f32x4*>(out + ((size_t)(b * CC + c)) * NN + n0 + lr * 4));
                }
            }
        }
    }
}

extern "C" void kernel_launch(void* const* d_in, const int* in_sizes, int n_in,
                              void* d_out, int out_size, void* d_ws, size_t ws_size,
                              hipStream_t stream) {
    const float* x     = (const float*)d_in[0];
    const float* gamma = (const float*)d_in[1];
    float* out = (float*)d_out;

    float* partialG = out;                                   // 8*64*4096 floats (8.4 MB)
    float* partialS = out + (size_t)BB * SPLIT1 * 4096;      // 8*64*64 floats
    float* Gsum     = partialS + BB * SPLIT1 * CC;           // 8*4096 floats
    float* offs     = (float*)d_ws;                          // 512 floats
    unsigned short* att = (unsigned short*)((char*)d_ws + 4096);  // 8*4096 bf16

    k1_gram<<<BB * SPLIT1, 256, 0, stream>>>(x, partialG, partialS);
    k2a_reduceG<<<(BB * 4096) / 256, 256, 0, stream>>>(partialG, Gsum);
    k2b_softmax<<<BB, 256, 0, stream>>>(partialS, Gsum, att, offs);
    k3_apply<<<BB * SPLIT3, 256, 0, stream>>>(x, att, offs, gamma, out);
}

// Round 10
// 126.500 us; speedup vs baseline: 1.3310x; 1.3310x over previous
//
#include <hip/hip_runtime.h>
#include <hip/hip_bf16.h>

typedef __attribute__((ext_vector_type(8))) short short8;
typedef __attribute__((ext_vector_type(4))) short short4v;
typedef __attribute__((ext_vector_type(4))) float f32x4;
typedef __attribute__((ext_vector_type(8))) __bf16 bf16x8;

#define BB 8
#define CC 64
#define NN 65536        // H*W = 256*256
#define SPLIT1 128      // k1 blocks per batch (1024 total = 4 blocks/CU)
#define COLS1 (NN / SPLIT1)   // 512 cols per k1 block
#define SPLIT3 128      // k3 blocks per batch

__device__ inline short f2bf(float f) {
    __hip_bfloat16 h = __float2bfloat16(f);
    return __builtin_bit_cast(short, h);
}

// --- MFMA wrapper: tolerate either short8 or bf16x8 builtin signature ---
template <typename V>
__device__ inline auto mfma_bf16_impl(V a, V b, f32x4 c, int)
    -> decltype(__builtin_amdgcn_mfma_f32_16x16x32_bf16(a, b, c, 0, 0, 0)) {
    return __builtin_amdgcn_mfma_f32_16x16x32_bf16(a, b, c, 0, 0, 0);
}
template <typename V>
__device__ inline f32x4 mfma_bf16_impl(V a, V b, f32x4 c, long) {
    bf16x8 a2 = __builtin_bit_cast(bf16x8, a);
    bf16x8 b2 = __builtin_bit_cast(bf16x8, b);
    return __builtin_amdgcn_mfma_f32_16x16x32_bf16(a2, b2, c, 0, 0, 0);
}
__device__ inline f32x4 mfma16(short8 a, short8 b, f32x4 c) {
    return mfma_bf16_impl(a, b, c, 0);
}

__device__ inline void gload8(const float* p, float* v) {
    const f32x4 u0 = *reinterpret_cast<const f32x4*>(p);
    const f32x4 u1 = *reinterpret_cast<const f32x4*>(p + 4);
    v[0] = u0[0]; v[1] = u0[1]; v[2] = u0[2]; v[3] = u0[3];
    v[4] = u1[0]; v[5] = u1[1]; v[6] = u1[2]; v[7] = u1[3];
}

__device__ inline short8 cvt8(const float* v) {
    short8 r;
#pragma unroll
    for (int j = 0; j < 8; ++j) r[j] = f2bf(v[j]);
    return r;
}

// ------- Kernel 1: partial Gram (bf16 MFMA) + channel sums -------------------
// NO LDS, NO BARRIERS: fragments load straight from global in MFMA layout.
// The 64x64-col working set is 16 KB -> the 4x within-block B reuse is served
// by L1 (32 KB/CU). R9 profile showed the LDS pipeline was barrier/latency
// bound at 2 blocks/CU (MfmaUtil 5.8%, VALU 20%, HBM 32%, occ 19%); removing
// the staging removes the drain point and lets the compiler pipeline loads.
__global__ __launch_bounds__(256) void k1_gram(const float* __restrict__ x,
                                               float* __restrict__ partialG,
                                               float* __restrict__ partialS) {
    const int blk  = blockIdx.x;
    const int b    = blk / SPLIT1;
    const int s    = blk % SPLIT1;
    const int tid  = threadIdx.x;
    const int w    = tid >> 6, lane = tid & 63, lg = lane >> 4, lr = lane & 15;
    const float* xb = x + (size_t)b * CC * NN;
    const int col0 = s * COLS1;

    // per-lane row pointers for the 4 dt row-groups (dt==w duplicates rowA)
    const float* rowp0 = xb + (size_t)(0 * 16 + lr) * NN + col0;
    const float* rowp1 = xb + (size_t)(1 * 16 + lr) * NN + col0;
    const float* rowp2 = xb + (size_t)(2 * 16 + lr) * NN + col0;
    const float* rowp3 = xb + (size_t)(3 * 16 + lr) * NN + col0;
    const float* rowA  = xb + (size_t)(w * 16 + lr) * NN + col0;

    f32x4 acc[4];
#pragma unroll
    for (int dt = 0; dt < 4; ++dt) acc[dt] = (f32x4){0.f, 0.f, 0.f, 0.f};
    float asum = 0.f;

    for (int c0 = lg * 8; c0 < COLS1; c0 += 32) {
        float av[8], bv0[8], bv1[8], bv2[8], bv3[8];
        gload8(rowA + c0, av);
        if (w != 0) gload8(rowp0 + c0, bv0);
        if (w != 1) gload8(rowp1 + c0, bv1);
        if (w != 2) gload8(rowp2 + c0, bv2);
        if (w != 3) gload8(rowp3 + c0, bv3);
#pragma unroll
        for (int j = 0; j < 8; ++j) asum += av[j];
        const short8 af = cvt8(av);
        const short8 bf0 = (w == 0) ? af : cvt8(bv0);
        const short8 bf1 = (w == 1) ? af : cvt8(bv1);
        const short8 bf2 = (w == 2) ? af : cvt8(bv2);
        const short8 bf3 = (w == 3) ? af : cvt8(bv3);
        acc[0] = mfma16(af, bf0, acc[0]);
        acc[1] = mfma16(af, bf1, acc[1]);
        acc[2] = mfma16(af, bf2, acc[2]);
        acc[3] = mfma16(af, bf3, acc[3]);
    }
    // ---- write partial Gram (C/D map: col=lane&15, row=(lane>>4)*4+reg) ----
#pragma unroll
    for (int dt = 0; dt < 4; ++dt) {
#pragma unroll
        for (int r = 0; r < 4; ++r) {
            const int c = w * 16 + lg * 4 + r;
            const int d = dt * 16 + lr;
            partialG[(size_t)blk * 4096 + c * 64 + d] = acc[dt][r];
        }
    }
    // ---- channel sums: reduce the lg quarters of each row ----
    float v = asum;
    v += __shfl_xor(v, 16);
    v += __shfl_xor(v, 32);
    if (lg == 0) partialS[blk * CC + w * 16 + lr] = v;
}

// ---------------- Kernel 2a: reduce partial Gram over splits ----------------
__global__ __launch_bounds__(256) void k2a_reduceG(const float* __restrict__ partialG,
                                                   float* __restrict__ Gsum) {
    const int gid = blockIdx.x * 256 + threadIdx.x;   // 0..32767
    const int b = gid >> 12;
    const int e = gid & 4095;
    float s = 0.f;
    for (int sp = 0; sp < SPLIT1; ++sp)
        s += partialG[(((size_t)(b * SPLIT1 + sp)) << 12) + e];
    Gsum[gid] = s;
}

// ------- Kernel 2b: means, energy, softmax -> att(bf16) + offsets -----------
__global__ __launch_bounds__(256) void k2b_softmax(const float* __restrict__ partialS,
                                                   const float* __restrict__ Gsum,
                                                   unsigned short* __restrict__ att,
                                                   float* __restrict__ offs) {
    __shared__ float mu[CC];
    __shared__ float ener[CC * CC];
    const int b = blockIdx.x;
    const int tid = threadIdx.x;
    if (tid < CC) {
        float s = 0.f;
        for (int sp = 0; sp < SPLIT1; ++sp) s += partialS[(b * SPLIT1 + sp) * CC + tid];
        mu[tid] = s * (1.f / NN);
    }
    __syncthreads();
    const float inv_n = 1.f / NN;
#pragma unroll
    for (int k = 0; k < 16; ++k) {
        const int e = tid + k * 256;
        const int c = e >> 6, d = e & 63;
        ener[e] = Gsum[(b << 12) + e] * inv_n - mu[c] * mu[d];
    }
    __syncthreads();
    const int w = tid >> 6, lane = tid & 63;
    for (int i = 0; i < 16; ++i) {
        const int c = w * 16 + i;
        const float v = ener[c * 64 + lane];
        float m = v;
        for (int off = 32; off > 0; off >>= 1) m = fmaxf(m, __shfl_xor(m, off));
        const float ev = __expf(v - m);
        float sum = ev;
        for (int off = 32; off > 0; off >>= 1) sum += __shfl_xor(sum, off);
        const float a = ev / sum;
        att[(b << 12) + c * 64 + lane] = (unsigned short)f2bf(a);
        float o = a * mu[lane];
        for (int off = 32; off > 0; off >>= 1) o += __shfl_xor(o, off);
        if (lane == 0) offs[b * CC + c] = o;
    }
}

// ---------------- Kernel 3: out = gamma * (A @ x - offset) ------------------
// Non-temporal stores keep x resident in Infinity Cache (134 MB < 256 MB L3).
__global__ __launch_bounds__(256) void k3_apply(const float* __restrict__ x,
                                                const unsigned short* __restrict__ att,
                                                const float* __restrict__ offs,
                                                const float* __restrict__ gamma,
                                                float* __restrict__ out) {
    const int blk  = blockIdx.x;
    const int b    = blk / SPLIT3;
    const int s    = blk % SPLIT3;
    const int tid  = threadIdx.x;
    const int w    = tid >> 6, lane = tid & 63, lg = lane >> 4, lr = lane & 15;
    const float g  = gamma[0];

    short8 afr[4][2];
#pragma unroll
    for (int ct = 0; ct < 4; ++ct)
#pragma unroll
        for (int ks = 0; ks < 2; ++ks)
            afr[ct][ks] = *reinterpret_cast<const short8*>(
                att + (((size_t)b) << 12) + (ct * 16 + lr) * 64 + ks * 32 + lg * 8);

    float offv[4][4];
#pragma unroll
    for (int ct = 0; ct < 4; ++ct)
#pragma unroll
        for (int r = 0; r < 4; ++r)
            offv[ct][r] = offs[b * CC + ct * 16 + lg * 4 + r];

    const int colblock = s * (NN / SPLIT3);
    const int GROUPS = (NN / SPLIT3) / (4 * 64);   // 64-col groups per wave (=2)
    for (int itg = 0; itg < GROUPS; ++itg) {
        const int n0 = colblock + (w * GROUPS + itg) * 64;
        f32x4 acc[4][4];
#pragma unroll
        for (int ph = 0; ph < 4; ++ph)
#pragma unroll
            for (int ct = 0; ct < 4; ++ct) acc[ph][ct] = (f32x4){0.f, 0.f, 0.f, 0.f};

#pragma unroll
        for (int ks = 0; ks < 2; ++ks) {
            short8 bfr[4];
            const int d0 = ks * 32 + lg * 8;
            const float* xp = x + ((size_t)(b * CC + d0)) * NN + n0 + lr * 4;
#pragma unroll
            for (int j = 0; j < 8; ++j) {
                const float4 v = *reinterpret_cast<const float4*>(xp + (size_t)j * NN);
                bfr[0][j] = f2bf(v.x);
                bfr[1][j] = f2bf(v.y);
                bfr[2][j] = f2bf(v.z);
                bfr[3][j] = f2bf(v.w);
            }
#pragma unroll
            for (int ct = 0; ct < 4; ++ct) {
#pragma unroll
                for (int ph = 0; ph < 4; ++ph)
                    acc[ph][ct] = mfma16(afr[ct][ks], bfr[ph], acc[ph][ct]);
            }
        }
#pragma unroll
        for (int ct = 0; ct < 4; ++ct) {
#pragma unroll
            for (int r = 0; r < 4; ++r) {
                const int c = ct * 16 + lg * 4 + r;
                const float o = offv[ct][r];
                f32x4 vs;
                vs[0] = g * (acc[0][ct][r] - o);
                vs[1] = g * (acc[1][ct][r] - o);
                vs[2] = g * (acc[2][ct][r] - o);
                vs[3] = g * (acc[3][ct][r] - o);
                __builtin_nontemporal_store(
                    vs, reinterpret_cast<f32x4*>(out + ((size_t)(b * CC + c)) * NN + n0 + lr * 4));
            }
        }
    }
}

extern "C" void kernel_launch(void* const* d_in, const int* in_sizes, int n_in,
                              void* d_out, int out_size, void* d_ws, size_t ws_size,
                              hipStream_t stream) {
    const float* x     = (const float*)d_in[0];
    const float* gamma = (const float*)d_in[1];
    float* out = (float*)d_out;

    // Large deterministic partials live at the FRONT of d_out (fully overwritten
    // by k3 afterwards). Only the small att/offs tables use d_ws.
    float* partialG = out;                                   // 8*128*4096 floats (16.8 MB)
    float* partialS = out + (size_t)BB * SPLIT1 * 4096;      // 8*128*64 floats
    float* Gsum     = partialS + BB * SPLIT1 * CC;           // 8*4096 floats
    float* offs     = (float*)d_ws;                          // 512 floats
    unsigned short* att = (unsigned short*)((char*)d_ws + 4096);  // 8*4096 bf16

    k1_gram<<<BB * SPLIT1, 256, 0, stream>>>(x, partialG, partialS);
    k2a_reduceG<<<(BB * 4096) / 256, 256, 0, stream>>>(partialG, Gsum);
    k2b_softmax<<<BB, 256, 0, stream>>>(partialS, Gsum, att, offs);
    k3_apply<<<BB * SPLIT3, 256, 0, stream>>>(x, att, offs, gamma, out);
}

// Round 11
// 91.401 us; speedup vs baseline: 1.8422x; 1.3840x over previous
//
#include <hip/hip_runtime.h>
#include <hip/hip_bf16.h>

typedef __attribute__((ext_vector_type(8))) short short8;
typedef __attribute__((ext_vector_type(4))) short short4v;
typedef __attribute__((ext_vector_type(4))) float f32x4;
typedef __attribute__((ext_vector_type(8))) __bf16 bf16x8;

#define BB 8
#define CC 64
#define NN 65536        // H*W = 256*256
#define SPLIT1 128      // k1 blocks per batch (1024 total = 4 blocks/CU of work)
#define COLS1 (NN / SPLIT1)   // 512 cols per k1 block
#define TC1 64                // cols per k1 tile: 64x64 bf16 = 8 KB per buffer
#define NT1 (COLS1 / TC1)     // 8 tiles per block
#define SPLIT3 128      // k3 blocks per batch (proven best)

__device__ inline short f2bf(float f) {
    __hip_bfloat16 h = __float2bfloat16(f);
    return __builtin_bit_cast(short, h);
}

// --- MFMA wrapper: tolerate either short8 or bf16x8 builtin signature ---
template <typename V>
__device__ inline auto mfma_bf16_impl(V a, V b, f32x4 c, int)
    -> decltype(__builtin_amdgcn_mfma_f32_16x16x32_bf16(a, b, c, 0, 0, 0)) {
    return __builtin_amdgcn_mfma_f32_16x16x32_bf16(a, b, c, 0, 0, 0);
}
template <typename V>
__device__ inline f32x4 mfma_bf16_impl(V a, V b, f32x4 c, long) {
    bf16x8 a2 = __builtin_bit_cast(bf16x8, a);
    bf16x8 b2 = __builtin_bit_cast(bf16x8, b);
    return __builtin_amdgcn_mfma_f32_16x16x32_bf16(a2, b2, c, 0, 0, 0);
}
__device__ inline f32x4 mfma16(short8 a, short8 b, f32x4 c) {
    return mfma_bf16_impl(a, b, c, 0);
}

// ------- Kernel 1 (v3): partial Gram + channel sums --------------------------
// bf16-in-LDS staging: reg-stage f32 (coalesced 16B/lane), cvt ONCE on the
// write side, MFMA reads short8 fragments directly (no read-side cvt).
// 2 x 8KB buffers; SPLIT1=128 -> 4 blocks/CU of work (R9: occupancy was
// work-limited at 2 blocks/CU, 19%). One __syncthreads per tile; prefetch
// loads stay in flight across the barrier (register loads drain at use, not
// at s_barrier; only the ds_writes need the lgkmcnt the barrier inserts).
__global__ __launch_bounds__(256) void k1_gram(const float* __restrict__ x,
                                               float* __restrict__ partialG,
                                               float* __restrict__ partialS) {
    __shared__ unsigned short tile2[2][CC * TC1];   // 2 x 8 KB
    const int blk  = blockIdx.x;
    const int b    = blk / SPLIT1;
    const int s    = blk % SPLIT1;
    const int tid  = threadIdx.x;
    const int w    = tid >> 6, lane = tid & 63, lg = lane >> 4, lr = lane & 15;
    const float* xb = x + (size_t)b * CC * NN;
    const int col0 = s * COLS1;

    const int lrow = tid >> 4;         // row within each 16-row group (0..15)
    const int lcolb = (tid & 15) * 16; // byte offset of this thread's 4 f32

    f32x4 acc[4];
#pragma unroll
    for (int dt = 0; dt < 4; ++dt) acc[dt] = (f32x4){0.f, 0.f, 0.f, 0.f};
    float sums[4] = {0.f, 0.f, 0.f, 0.f};   // f32 sums of rows i*16+lrow

    // prologue: load tile 0 into registers
    f32x4 pf0, pf1, pf2, pf3;
    {
        const char* base = (const char*)(xb + col0) + lcolb;
        pf0 = *reinterpret_cast<const f32x4*>(base + (size_t)(0 * 16 + lrow) * NN * 4);
        pf1 = *reinterpret_cast<const f32x4*>(base + (size_t)(1 * 16 + lrow) * NN * 4);
        pf2 = *reinterpret_cast<const f32x4*>(base + (size_t)(2 * 16 + lrow) * NN * 4);
        pf3 = *reinterpret_cast<const f32x4*>(base + (size_t)(3 * 16 + lrow) * NN * 4);
    }

    for (int t = 0; t < NT1; ++t) {
        // ---- cvt + ds_write tile t (b64, swizzled) + f32 sums ----
        char* lbase = (char*)tile2[t & 1];
#pragma unroll
        for (int i = 0; i < 4; ++i) {
            const f32x4 v = (i == 0) ? pf0 : (i == 1) ? pf1 : (i == 2) ? pf2 : pf3;
            const int row = i * 16 + lrow;
            sums[i] += v[0] + v[1] + v[2] + v[3];
            short4v sv;
            sv.x = f2bf(v[0]); sv.y = f2bf(v[1]); sv.z = f2bf(v[2]); sv.w = f2bf(v[3]);
            const int addr = row * 128 + (((tid & 15) * 8) ^ ((row & 7) << 4));
            *reinterpret_cast<short4v*>(lbase + addr) = sv;
        }
        // ---- issue prefetch for tile t+1 (consumed after the barrier) ----
        if (t + 1 < NT1) {
            const char* base = (const char*)(xb + col0 + (t + 1) * TC1) + lcolb;
            pf0 = *reinterpret_cast<const f32x4*>(base + (size_t)(0 * 16 + lrow) * NN * 4);
            pf1 = *reinterpret_cast<const f32x4*>(base + (size_t)(1 * 16 + lrow) * NN * 4);
            pf2 = *reinterpret_cast<const f32x4*>(base + (size_t)(2 * 16 + lrow) * NN * 4);
            pf3 = *reinterpret_cast<const f32x4*>(base + (size_t)(3 * 16 + lrow) * NN * 4);
        }
        __syncthreads();
        // ---- MFMA phase: read short8 fragments straight from LDS ----
        const char* buf = (const char*)tile2[t & 1];
#pragma unroll
        for (int kk = 0; kk < TC1 / 32; ++kk) {
            const int cb = (kk * 32 + lg * 8) * 2;   // byte col offset
            const int ra = w * 16 + lr;
            const short8 af = *reinterpret_cast<const short8*>(
                buf + ra * 128 + (cb ^ ((ra & 7) << 4)));
#pragma unroll
            for (int dt = 0; dt < 4; ++dt) {
                short8 bf;
                if (dt == w) {
                    bf = af;
                } else {
                    const int rb = dt * 16 + lr;
                    bf = *reinterpret_cast<const short8*>(
                        buf + rb * 128 + (cb ^ ((rb & 7) << 4)));
                }
                acc[dt] = mfma16(af, bf, acc[dt]);
            }
        }
        __syncthreads();   // readers of buf[t&1] done before its t+2 rewrite
    }
    // ---- write partial Gram (C/D map: col=lane&15, row=(lane>>4)*4+reg) ----
#pragma unroll
    for (int dt = 0; dt < 4; ++dt) {
#pragma unroll
        for (int r = 0; r < 4; ++r) {
            const int c = w * 16 + lg * 4 + r;
            const int d = dt * 16 + lr;
            partialG[(size_t)blk * 4096 + c * 64 + d] = acc[dt][r];
        }
    }
    // ---- channel sums: reduce across the 16 threads sharing each row ----
#pragma unroll
    for (int i = 0; i < 4; ++i) {
        float v = sums[i];
        v += __shfl_xor(v, 1);
        v += __shfl_xor(v, 2);
        v += __shfl_xor(v, 4);
        v += __shfl_xor(v, 8);
        if ((tid & 15) == 0)
            partialS[blk * CC + i * 16 + lrow] = v;
    }
}

// ---------------- Kernel 2a: reduce partial Gram over splits ----------------
__global__ __launch_bounds__(256) void k2a_reduceG(const float* __restrict__ partialG,
                                                   float* __restrict__ Gsum) {
    const int gid = blockIdx.x * 256 + threadIdx.x;   // 0..32767
    const int b = gid >> 12;
    const int e = gid & 4095;
    float s = 0.f;
    for (int sp = 0; sp < SPLIT1; ++sp)
        s += partialG[(((size_t)(b * SPLIT1 + sp)) << 12) + e];
    Gsum[gid] = s;
}

// ------- Kernel 2b: means, energy, softmax -> att(bf16) + offsets -----------
__global__ __launch_bounds__(256) void k2b_softmax(const float* __restrict__ partialS,
                                                   const float* __restrict__ Gsum,
                                                   unsigned short* __restrict__ att,
                                                   float* __restrict__ offs) {
    __shared__ float mu[CC];
    __shared__ float ener[CC * CC];
    const int b = blockIdx.x;
    const int tid = threadIdx.x;
    if (tid < CC) {
        float s = 0.f;
        for (int sp = 0; sp < SPLIT1; ++sp) s += partialS[(b * SPLIT1 + sp) * CC + tid];
        mu[tid] = s * (1.f / NN);
    }
    __syncthreads();
    const float inv_n = 1.f / NN;
#pragma unroll
    for (int k = 0; k < 16; ++k) {
        const int e = tid + k * 256;
        const int c = e >> 6, d = e & 63;
        ener[e] = Gsum[(b << 12) + e] * inv_n - mu[c] * mu[d];
    }
    __syncthreads();
    const int w = tid >> 6, lane = tid & 63;
    for (int i = 0; i < 16; ++i) {
        const int c = w * 16 + i;
        const float v = ener[c * 64 + lane];
        float m = v;
        for (int off = 32; off > 0; off >>= 1) m = fmaxf(m, __shfl_xor(m, off));
        const float ev = __expf(v - m);
        float sum = ev;
        for (int off = 32; off > 0; off >>= 1) sum += __shfl_xor(sum, off);
        const float a = ev / sum;
        att[(b << 12) + c * 64 + lane] = (unsigned short)f2bf(a);
        float o = a * mu[lane];
        for (int off = 32; off > 0; off >>= 1) o += __shfl_xor(o, off);
        if (lane == 0) offs[b * CC + c] = o;
    }
}

// ---------------- Kernel 3: out = gamma * (A @ x - offset) ------------------
// Non-temporal stores keep x resident in Infinity Cache (134 MB < 256 MB L3).
__global__ __launch_bounds__(256) void k3_apply(const float* __restrict__ x,
                                                const unsigned short* __restrict__ att,
                                                const float* __restrict__ offs,
                                                const float* __restrict__ gamma,
                                                float* __restrict__ out) {
    const int blk  = blockIdx.x;
    const int b    = blk / SPLIT3;
    const int s    = blk % SPLIT3;
    const int tid  = threadIdx.x;
    const int w    = tid >> 6, lane = tid & 63, lg = lane >> 4, lr = lane & 15;
    const float g  = gamma[0];

    short8 afr[4][2];
#pragma unroll
    for (int ct = 0; ct < 4; ++ct)
#pragma unroll
        for (int ks = 0; ks < 2; ++ks)
            afr[ct][ks] = *reinterpret_cast<const short8*>(
                att + (((size_t)b) << 12) + (ct * 16 + lr) * 64 + ks * 32 + lg * 8);

    float offv[4][4];
#pragma unroll
    for (int ct = 0; ct < 4; ++ct)
#pragma unroll
        for (int r = 0; r < 4; ++r)
            offv[ct][r] = offs[b * CC + ct * 16 + lg * 4 + r];

    const int colblock = s * (NN / SPLIT3);
    const int GROUPS = (NN / SPLIT3) / (4 * 64);   // 64-col groups per wave (=2)
    for (int itg = 0; itg < GROUPS; ++itg) {
        const int n0 = colblock + (w * GROUPS + itg) * 64;
        f32x4 acc[4][4];
#pragma unroll
        for (int ph = 0; ph < 4; ++ph)
#pragma unroll
            for (int ct = 0; ct < 4; ++ct) acc[ph][ct] = (f32x4){0.f, 0.f, 0.f, 0.f};

#pragma unroll
        for (int ks = 0; ks < 2; ++ks) {
            short8 bfr[4];
            const int d0 = ks * 32 + lg * 8;
            const float* xp = x + ((size_t)(b * CC + d0)) * NN + n0 + lr * 4;
#pragma unroll
            for (int j = 0; j < 8; ++j) {
                const float4 v = *reinterpret_cast<const float4*>(xp + (size_t)j * NN);
                bfr[0][j] = f2bf(v.x);
                bfr[1][j] = f2bf(v.y);
                bfr[2][j] = f2bf(v.z);
                bfr[3][j] = f2bf(v.w);
            }
#pragma unroll
            for (int ct = 0; ct < 4; ++ct) {
#pragma unroll
                for (int ph = 0; ph < 4; ++ph)
                    acc[ph][ct] = mfma16(afr[ct][ks], bfr[ph], acc[ph][ct]);
            }
        }
#pragma unroll
        for (int ct = 0; ct < 4; ++ct) {
#pragma unroll
            for (int r = 0; r < 4; ++r) {
                const int c = ct * 16 + lg * 4 + r;
                const float o = offv[ct][r];
                f32x4 vs;
                vs[0] = g * (acc[0][ct][r] - o);
                vs[1] = g * (acc[1][ct][r] - o);
                vs[2] = g * (acc[2][ct][r] - o);
                vs[3] = g * (acc[3][ct][r] - o);
                __builtin_nontemporal_store(
                    vs, reinterpret_cast<f32x4*>(out + ((size_t)(b * CC + c)) * NN + n0 + lr * 4));
            }
        }
    }
}

extern "C" void kernel_launch(void* const* d_in, const int* in_sizes, int n_in,
                              void* d_out, int out_size, void* d_ws, size_t ws_size,
                              hipStream_t stream) {
    const float* x     = (const float*)d_in[0];
    const float* gamma = (const float*)d_in[1];
    float* out = (float*)d_out;

    // Large deterministic partials live at the FRONT of d_out (fully overwritten
    // by k3 afterwards). Only the small att/offs tables use d_ws.
    float* partialG = out;                                   // 8*128*4096 floats (16.8 MB)
    float* partialS = out + (size_t)BB * SPLIT1 * 4096;      // 8*128*64 floats
    float* Gsum     = partialS + BB * SPLIT1 * CC;           // 8*4096 floats
    float* offs     = (float*)d_ws;                          // 512 floats
    unsigned short* att = (unsigned short*)((char*)d_ws + 4096);  // 8*4096 bf16

    k1_gram<<<BB * SPLIT1, 256, 0, stream>>>(x, partialG, partialS);
    k2a_reduceG<<<(BB * 4096) / 256, 256, 0, stream>>>(partialG, Gsum);
    k2b_softmax<<<BB, 256, 0, stream>>>(partialS, Gsum, att, offs);
    k3_apply<<<BB * SPLIT3, 256, 0, stream>>>(x, att, offs, gamma, out);
}

// Round 12
// 89.113 us; speedup vs baseline: 1.8895x; 1.0257x over previous
//
#include <hip/hip_runtime.h>
#include <hip/hip_bf16.h>

typedef __attribute__((ext_vector_type(8))) short short8;
typedef __attribute__((ext_vector_type(4))) short short4v;
typedef __attribute__((ext_vector_type(4))) float f32x4;
typedef __attribute__((ext_vector_type(8))) __bf16 bf16x8;

#define BB 8
#define CC 64
#define NN 65536        // H*W = 256*256
#define SPLIT1 128      // k1 blocks per batch (1024 total = 4 blocks/CU resident)
#define COLS1 (NN / SPLIT1)   // 512 cols per k1 block
#define TILE_C 64             // fp32 tile cols: 64 x 64 x 4B = 16 KB per buffer
#define NT1 (COLS1 / TILE_C)  // 8 tiles per block
#define SPLIT3 128      // k3 blocks per batch

__device__ inline short f2bf(float f) {
    __hip_bfloat16 h = __float2bfloat16(f);
    return __builtin_bit_cast(short, h);
}

// --- MFMA wrapper: tolerate either short8 or bf16x8 builtin signature ---
template <typename V>
__device__ inline auto mfma_bf16_impl(V a, V b, f32x4 c, int)
    -> decltype(__builtin_amdgcn_mfma_f32_16x16x32_bf16(a, b, c, 0, 0, 0)) {
    return __builtin_amdgcn_mfma_f32_16x16x32_bf16(a, b, c, 0, 0, 0);
}
template <typename V>
__device__ inline f32x4 mfma_bf16_impl(V a, V b, f32x4 c, long) {
    bf16x8 a2 = __builtin_bit_cast(bf16x8, a);
    bf16x8 b2 = __builtin_bit_cast(bf16x8, b);
    return __builtin_amdgcn_mfma_f32_16x16x32_bf16(a2, b2, c, 0, 0, 0);
}
__device__ inline f32x4 mfma16(short8 a, short8 b, f32x4 c) {
    return mfma_bf16_impl(a, b, c, 0);
}

// ---- async global->LDS staging of one 64x64 fp32 tile (16 KB) ---------------
// LDS dest LINEAR (HW requirement: uniform base + lane*16). XOR swizzle
// ((row&15) on the 16B slot) applied to the GLOBAL source address
// (rule #21: pre-swizzled source + same-involution read).
__device__ inline void stage_tile(const float* __restrict__ xb, int colbase,
                                  float* buf, int tid) {
    const int slot  = tid & 15;          // 16-B slot within the 256-B row
    const int rg    = tid >> 4;          // row within each 16-row group
    const int gbyte = (slot ^ rg) << 4;  // pre-swizzled source byte
#pragma unroll
    for (int i = 0; i < 4; ++i) {
        const int row = i * 16 + rg;     // 0..63
        const float* gp = xb + (size_t)row * NN + colbase + (gbyte >> 2);
        float* lp = buf + i * 1024 + tid * 4;   // linear LDS dest
        __builtin_amdgcn_global_load_lds(
            (const __attribute__((address_space(1))) void*)gp,
            (__attribute__((address_space(3))) void*)lp, 16, 0, 0);
    }
}

// read 8 consecutive fp32 tile elements (row, cols c0..c0+7) through the swizzle
__device__ inline void lds_read8(const float* buf, int row, int c0, float* v) {
    const char* rb = (const char*)(buf + row * TILE_C);
    const int swz = (row & 15) << 4;
    const f32x4 u0 = *reinterpret_cast<const f32x4*>(rb + ((c0 * 4) ^ swz));
    const f32x4 u1 = *reinterpret_cast<const f32x4*>(rb + (((c0 * 4) + 16) ^ swz));
    v[0] = u0[0]; v[1] = u0[1]; v[2] = u0[2]; v[3] = u0[3];
    v[4] = u1[0]; v[5] = u1[1]; v[6] = u1[2]; v[7] = u1[3];
}

__device__ inline short8 cvt8(const float* v) {
    short8 r;
#pragma unroll
    for (int j = 0; j < 8; ++j) r[j] = f2bf(v[j]);
    return r;
}

// ------- Kernel 1: partial Gram (bf16 MFMA) + channel sums -------------------
// R6's proven global_load_lds double-buffer + __syncthreads loop, at HALF the
// LDS (2x16KB) and DOUBLE the blocks (4/CU resident): cross-block wave overlap
// hides the per-tile barrier drain (R9: k1 was latency-bound, nothing >32%).
__global__ __launch_bounds__(256) void k1_gram(const float* __restrict__ x,
                                               float* __restrict__ partialG,
                                               float* __restrict__ partialS) {
    __shared__ float lbuf[2][CC * TILE_C];   // 2 x 16 KB
    const int blk  = blockIdx.x;
    const int b    = blk / SPLIT1;
    const int s    = blk % SPLIT1;
    const int tid  = threadIdx.x;
    const int w    = tid >> 6, lane = tid & 63, lg = lane >> 4, lr = lane & 15;
    const float* xb = x + (size_t)b * CC * NN;
    const int colbase0 = s * COLS1;

    f32x4 acc[4];
#pragma unroll
    for (int dt = 0; dt < 4; ++dt) acc[dt] = (f32x4){0.f, 0.f, 0.f, 0.f};
    float asum = 0.f;

    stage_tile(xb, colbase0, lbuf[0], tid);
    __syncthreads();

    for (int t = 0; t < NT1; ++t) {
        if (t + 1 < NT1)
            stage_tile(xb, colbase0 + (t + 1) * TILE_C, lbuf[(t + 1) & 1], tid);
        const float* buf = lbuf[t & 1];
#pragma unroll
        for (int kk = 0; kk < TILE_C / 32; ++kk) {
            const int c0 = kk * 32 + lg * 8;
            float av[8];
            lds_read8(buf, w * 16 + lr, c0, av);
#pragma unroll
            for (int j = 0; j < 8; ++j) asum += av[j];
            const short8 af = cvt8(av);
#pragma unroll
            for (int dt = 0; dt < 4; ++dt) {
                short8 bf;
                if (dt == w) {           // wave-uniform: B-row == A-row, reuse
                    bf = af;
                } else {
                    float bv[8];
                    lds_read8(buf, dt * 16 + lr, c0, bv);
                    bf = cvt8(bv);
                }
                acc[dt] = mfma16(af, bf, acc[dt]);
            }
        }
        __syncthreads();
    }
    // ---- write partial Gram (C/D map: col=lane&15, row=(lane>>4)*4+reg) ----
#pragma unroll
    for (int dt = 0; dt < 4; ++dt) {
#pragma unroll
        for (int r = 0; r < 4; ++r) {
            const int c = w * 16 + lg * 4 + r;
            const int d = dt * 16 + lr;
            partialG[(size_t)blk * 4096 + c * 64 + d] = acc[dt][r];
        }
    }
    // ---- channel sums: reduce the lg quarters of each row ----
    float v = asum;
    v += __shfl_xor(v, 16);
    v += __shfl_xor(v, 32);
    if (lg == 0) partialS[blk * CC + w * 16 + lr] = v;
}

// ---------------- Kernel 2a: reduce partial Gram over splits ----------------
__global__ __launch_bounds__(256) void k2a_reduceG(const float* __restrict__ partialG,
                                                   float* __restrict__ Gsum) {
    const int gid = blockIdx.x * 256 + threadIdx.x;   // 0..32767
    const int b = gid >> 12;
    const int e = gid & 4095;
    float s = 0.f;
    for (int sp = 0; sp < SPLIT1; ++sp)
        s += partialG[(((size_t)(b * SPLIT1 + sp)) << 12) + e];
    Gsum[gid] = s;
}

// ------- Kernel 2b: means, energy, softmax -> att(bf16) + offsets -----------
__global__ __launch_bounds__(256) void k2b_softmax(const float* __restrict__ partialS,
                                                   const float* __restrict__ Gsum,
                                                   unsigned short* __restrict__ att,
                                                   float* __restrict__ offs) {
    __shared__ float mu[CC];
    __shared__ float ener[CC * CC];
    const int b = blockIdx.x;
    const int tid = threadIdx.x;
    if (tid < CC) {
        float s = 0.f;
        for (int sp = 0; sp < SPLIT1; ++sp) s += partialS[(b * SPLIT1 + sp) * CC + tid];
        mu[tid] = s * (1.f / NN);
    }
    __syncthreads();
    const float inv_n = 1.f / NN;
#pragma unroll
    for (int k = 0; k < 16; ++k) {
        const int e = tid + k * 256;
        const int c = e >> 6, d = e & 63;
        ener[e] = Gsum[(b << 12) + e] * inv_n - mu[c] * mu[d];
    }
    __syncthreads();
    const int w = tid >> 6, lane = tid & 63;
    for (int i = 0; i < 16; ++i) {
        const int c = w * 16 + i;
        const float v = ener[c * 64 + lane];
        float m = v;
        for (int off = 32; off > 0; off >>= 1) m = fmaxf(m, __shfl_xor(m, off));
        const float ev = __expf(v - m);
        float sum = ev;
        for (int off = 32; off > 0; off >>= 1) sum += __shfl_xor(sum, off);
        const float a = ev / sum;
        att[(b << 12) + c * 64 + lane] = (unsigned short)f2bf(a);
        float o = a * mu[lane];
        for (int off = 32; off > 0; off >>= 1) o += __shfl_xor(o, off);
        if (lane == 0) offs[b * CC + c] = o;
    }
}

// ---------------- Kernel 3: out = gamma * (A @ x - offset) ------------------
// Non-temporal stores keep x resident in Infinity Cache (134 MB < 256 MB L3).
__global__ __launch_bounds__(256) void k3_apply(const float* __restrict__ x,
                                                const unsigned short* __restrict__ att,
                                                const float* __restrict__ offs,
                                                const float* __restrict__ gamma,
                                                float* __restrict__ out) {
    const int blk  = blockIdx.x;
    const int b    = blk / SPLIT3;
    const int s    = blk % SPLIT3;
    const int tid  = threadIdx.x;
    const int w    = tid >> 6, lane = tid & 63, lg = lane >> 4, lr = lane & 15;
    const float g  = gamma[0];

    short8 afr[4][2];
#pragma unroll
    for (int ct = 0; ct < 4; ++ct)
#pragma unroll
        for (int ks = 0; ks < 2; ++ks)
            afr[ct][ks] = *reinterpret_cast<const short8*>(
                att + (((size_t)b) << 12) + (ct * 16 + lr) * 64 + ks * 32 + lg * 8);

    float offv[4][4];
#pragma unroll
    for (int ct = 0; ct < 4; ++ct)
#pragma unroll
        for (int r = 0; r < 4; ++r)
            offv[ct][r] = offs[b * CC + ct * 16 + lg * 4 + r];

    const int colblock = s * (NN / SPLIT3);
    const int GROUPS = (NN / SPLIT3) / (4 * 64);   // 64-col groups per wave (=2)
    for (int itg = 0; itg < GROUPS; ++itg) {
        const int n0 = colblock + (w * GROUPS + itg) * 64;
        f32x4 acc[4][4];
#pragma unroll
        for (int ph = 0; ph < 4; ++ph)
#pragma unroll
            for (int ct = 0; ct < 4; ++ct) acc[ph][ct] = (f32x4){0.f, 0.f, 0.f, 0.f};

#pragma unroll
        for (int ks = 0; ks < 2; ++ks) {
            short8 bfr[4];
            const int d0 = ks * 32 + lg * 8;
            const float* xp = x + ((size_t)(b * CC + d0)) * NN + n0 + lr * 4;
#pragma unroll
            for (int j = 0; j < 8; ++j) {
                const float4 v = *reinterpret_cast<const float4*>(xp + (size_t)j * NN);
                bfr[0][j] = f2bf(v.x);
                bfr[1][j] = f2bf(v.y);
                bfr[2][j] = f2bf(v.z);
                bfr[3][j] = f2bf(v.w);
            }
#pragma unroll
            for (int ct = 0; ct < 4; ++ct) {
#pragma unroll
                for (int ph = 0; ph < 4; ++ph)
                    acc[ph][ct] = mfma16(afr[ct][ks], bfr[ph], acc[ph][ct]);
            }
        }
#pragma unroll
        for (int ct = 0; ct < 4; ++ct) {
#pragma unroll
            for (int r = 0; r < 4; ++r) {
                const int c = ct * 16 + lg * 4 + r;
                const float o = offv[ct][r];
                f32x4 vs;
                vs[0] = g * (acc[0][ct][r] - o);
                vs[1] = g * (acc[1][ct][r] - o);
                vs[2] = g * (acc[2][ct][r] - o);
                vs[3] = g * (acc[3][ct][r] - o);
                __builtin_nontemporal_store(
                    vs, reinterpret_cast<f32x4*>(out + ((size_t)(b * CC + c)) * NN + n0 + lr * 4));
            }
        }
    }
}

extern "C" void kernel_launch(void* const* d_in, const int* in_sizes, int n_in,
                              void* d_out, int out_size, void* d_ws, size_t ws_size,
                              hipStream_t stream) {
    const float* x     = (const float*)d_in[0];
    const float* gamma = (const float*)d_in[1];
    float* out = (float*)d_out;

    // Large deterministic partials live at the FRONT of d_out (fully overwritten
    // by k3 afterwards). Only the small att/offs tables use d_ws.
    float* partialG = out;                                   // 8*128*4096 floats (16.8 MB)
    float* partialS = out + (size_t)BB * SPLIT1 * 4096;      // 8*128*64 floats
    float* Gsum     = partialS + BB * SPLIT1 * CC;           // 8*4096 floats
    float* offs     = (float*)d_ws;                          // 512 floats
    unsigned short* att = (unsigned short*)((char*)d_ws + 4096);  // 8*4096 bf16

    k1_gram<<<BB * SPLIT1, 256, 0, stream>>>(x, partialG, partialS);
    k2a_reduceG<<<(BB * 4096) / 256, 256, 0, stream>>>(partialG, Gsum);
    k2b_softmax<<<BB, 256, 0, stream>>>(partialS, Gsum, att, offs);
    k3_apply<<<BB * SPLIT3, 256, 0, stream>>>(x, att, offs, gamma, out);
}